// Round 4
// baseline (143.547 us; speedup 1.0000x reference)
//
#include <hip/hip_runtime.h>

// Row-wise max -> mask (input == row_max) as int32.
// Input: [N=200704, D=512] fp32. Output: [N, 512] int32.
// One wave processes 4 rows per grid-stride iteration:
//   8 grouped nt loads (8 KB read burst) -> 4 interleaved butterfly reduces
//   -> 8 grouped nt stores (8 KB write burst).
// Grouping same-direction traffic maximizes HBM burst length.

typedef float f32x4 __attribute__((ext_vector_type(4)));
typedef int   i32x4 __attribute__((ext_vector_type(4)));

__global__ __launch_bounds__(256) void rowmax_mask_kernel(
    const float* __restrict__ in, int* __restrict__ out, int nrows) {
    const int lane   = threadIdx.x & 63;
    const int gwave  = (blockIdx.x * 256 + threadIdx.x) >> 6;
    const int nwaves = (gridDim.x * 256) >> 6;

    // nrows = 200704 is divisible by 4; row is always a multiple of 4.
    for (int row = gwave * 4; row < nrows; row += nwaves * 4) {
        const f32x4* r0 = reinterpret_cast<const f32x4*>(in + (size_t)row * 512);
        const f32x4* r1 = reinterpret_cast<const f32x4*>(in + (size_t)(row + 1) * 512);
        const f32x4* r2 = reinterpret_cast<const f32x4*>(in + (size_t)(row + 2) * 512);
        const f32x4* r3 = reinterpret_cast<const f32x4*>(in + (size_t)(row + 3) * 512);

        // 8 independent 16B loads: one 8 KB read burst per wave.
        f32x4 a0 = __builtin_nontemporal_load(r0 + lane);
        f32x4 b0 = __builtin_nontemporal_load(r0 + lane + 64);
        f32x4 a1 = __builtin_nontemporal_load(r1 + lane);
        f32x4 b1 = __builtin_nontemporal_load(r1 + lane + 64);
        f32x4 a2 = __builtin_nontemporal_load(r2 + lane);
        f32x4 b2 = __builtin_nontemporal_load(r2 + lane + 64);
        f32x4 a3 = __builtin_nontemporal_load(r3 + lane);
        f32x4 b3 = __builtin_nontemporal_load(r3 + lane + 64);

        float m0 = fmaxf(fmaxf(fmaxf(a0.x, a0.y), fmaxf(a0.z, a0.w)),
                         fmaxf(fmaxf(b0.x, b0.y), fmaxf(b0.z, b0.w)));
        float m1 = fmaxf(fmaxf(fmaxf(a1.x, a1.y), fmaxf(a1.z, a1.w)),
                         fmaxf(fmaxf(b1.x, b1.y), fmaxf(b1.z, b1.w)));
        float m2 = fmaxf(fmaxf(fmaxf(a2.x, a2.y), fmaxf(a2.z, a2.w)),
                         fmaxf(fmaxf(b2.x, b2.y), fmaxf(b2.z, b2.w)));
        float m3 = fmaxf(fmaxf(fmaxf(a3.x, a3.y), fmaxf(a3.z, a3.w)),
                         fmaxf(fmaxf(b3.x, b3.y), fmaxf(b3.z, b3.w)));

        // Four interleaved independent butterfly chains.
        #pragma unroll
        for (int off = 32; off > 0; off >>= 1) {
            m0 = fmaxf(m0, __shfl_xor(m0, off, 64));
            m1 = fmaxf(m1, __shfl_xor(m1, off, 64));
            m2 = fmaxf(m2, __shfl_xor(m2, off, 64));
            m3 = fmaxf(m3, __shfl_xor(m3, off, 64));
        }

        i32x4 oa0, ob0, oa1, ob1, oa2, ob2, oa3, ob3;
        oa0.x = (a0.x == m0); oa0.y = (a0.y == m0); oa0.z = (a0.z == m0); oa0.w = (a0.w == m0);
        ob0.x = (b0.x == m0); ob0.y = (b0.y == m0); ob0.z = (b0.z == m0); ob0.w = (b0.w == m0);
        oa1.x = (a1.x == m1); oa1.y = (a1.y == m1); oa1.z = (a1.z == m1); oa1.w = (a1.w == m1);
        ob1.x = (b1.x == m1); ob1.y = (b1.y == m1); ob1.z = (b1.z == m1); ob1.w = (b1.w == m1);
        oa2.x = (a2.x == m2); oa2.y = (a2.y == m2); oa2.z = (a2.z == m2); oa2.w = (a2.w == m2);
        ob2.x = (b2.x == m2); ob2.y = (b2.y == m2); ob2.z = (b2.z == m2); ob2.w = (b2.w == m2);
        oa3.x = (a3.x == m3); oa3.y = (a3.y == m3); oa3.z = (a3.z == m3); oa3.w = (a3.w == m3);
        ob3.x = (b3.x == m3); ob3.y = (b3.y == m3); ob3.z = (b3.z == m3); ob3.w = (b3.w == m3);

        i32x4* w0 = reinterpret_cast<i32x4*>(out + (size_t)row * 512);
        i32x4* w1 = reinterpret_cast<i32x4*>(out + (size_t)(row + 1) * 512);
        i32x4* w2 = reinterpret_cast<i32x4*>(out + (size_t)(row + 2) * 512);
        i32x4* w3 = reinterpret_cast<i32x4*>(out + (size_t)(row + 3) * 512);

        // 8 grouped 16B stores: one 8 KB write burst per wave.
        __builtin_nontemporal_store(oa0, w0 + lane);
        __builtin_nontemporal_store(ob0, w0 + lane + 64);
        __builtin_nontemporal_store(oa1, w1 + lane);
        __builtin_nontemporal_store(ob1, w1 + lane + 64);
        __builtin_nontemporal_store(oa2, w2 + lane);
        __builtin_nontemporal_store(ob2, w2 + lane + 64);
        __builtin_nontemporal_store(oa3, w3 + lane);
        __builtin_nontemporal_store(ob3, w3 + lane + 64);
    }
}

extern "C" void kernel_launch(void* const* d_in, const int* in_sizes, int n_in,
                              void* d_out, int out_size, void* d_ws, size_t ws_size,
                              hipStream_t stream) {
    const float* in = (const float*)d_in[0];
    int* out = (int*)d_out;
    const int D = 512;
    const int nrows = in_sizes[0] / D;   // 200704
    int grid = 2048;                     // ~8 blocks/CU, persistent
    const int max_needed = (nrows + 15) / 16;  // 4 waves/block * 4 rows/wave
    if (grid > max_needed) grid = max_needed;
    rowmax_mask_kernel<<<grid, 256, 0, stream>>>(in, out, nrows);
}

// Round 5
// 141.078 us; speedup vs baseline: 1.0175x; 1.0175x over previous
//
#include <hip/hip_runtime.h>

// Row-wise max -> mask (input == row_max) as int32.
// Input: [N=200704, D=512] fp32. Output: [N, 512] int32.
// One wave per row-pair: 64 lanes x 8 floats = 512 elements per row.
// Persistent grid-stride waves (2048 blocks = exactly 32 waves/CU),
// software-pipelined next-iteration loads, non-temporal streams.
// Best measured: 140.96 us = 93% of the 6.29 TB/s mixed-stream ceiling
// (822 MB mandatory traffic; floor ~131 us). R4's 4-row burst grouping
// and R1's one-shot grid both regressed — this is the plateau structure.

typedef float f32x4 __attribute__((ext_vector_type(4)));
typedef int   i32x4 __attribute__((ext_vector_type(4)));

__global__ __launch_bounds__(256) void rowmax_mask_kernel(
    const float* __restrict__ in, int* __restrict__ out, int nrows) {
    const int lane   = threadIdx.x & 63;
    const int gwave  = (blockIdx.x * 256 + threadIdx.x) >> 6;
    const int nwaves = (gridDim.x * 256) >> 6;
    const int stride = nwaves * 2;   // rows per grid-stride step

    int row = gwave * 2;
    if (row >= nrows) return;

    // Prologue: issue first iteration's loads.
    const f32x4* r0 = reinterpret_cast<const f32x4*>(in + (size_t)row * 512);
    const f32x4* r1 = reinterpret_cast<const f32x4*>(in + (size_t)(row + 1) * 512);
    f32x4 a0 = __builtin_nontemporal_load(r0 + lane);
    f32x4 b0 = __builtin_nontemporal_load(r0 + lane + 64);
    f32x4 a1 = __builtin_nontemporal_load(r1 + lane);
    f32x4 b1 = __builtin_nontemporal_load(r1 + lane + 64);

    while (true) {
        // Issue NEXT iteration's loads before touching current data.
        const int nrow = row + stride;
        f32x4 na0 = {}, nb0 = {}, na1 = {}, nb1 = {};
        if (nrow < nrows) {
            const f32x4* p0 = reinterpret_cast<const f32x4*>(in + (size_t)nrow * 512);
            const f32x4* p1 = reinterpret_cast<const f32x4*>(in + (size_t)(nrow + 1) * 512);
            na0 = __builtin_nontemporal_load(p0 + lane);
            nb0 = __builtin_nontemporal_load(p0 + lane + 64);
            na1 = __builtin_nontemporal_load(p1 + lane);
            nb1 = __builtin_nontemporal_load(p1 + lane + 64);
        }

        // Reduce current rows.
        float m0 = fmaxf(fmaxf(fmaxf(a0.x, a0.y), fmaxf(a0.z, a0.w)),
                         fmaxf(fmaxf(b0.x, b0.y), fmaxf(b0.z, b0.w)));
        float m1 = fmaxf(fmaxf(fmaxf(a1.x, a1.y), fmaxf(a1.z, a1.w)),
                         fmaxf(fmaxf(b1.x, b1.y), fmaxf(b1.z, b1.w)));
        #pragma unroll
        for (int off = 32; off > 0; off >>= 1) {
            m0 = fmaxf(m0, __shfl_xor(m0, off, 64));
            m1 = fmaxf(m1, __shfl_xor(m1, off, 64));
        }

        i32x4 oa0, ob0, oa1, ob1;
        oa0.x = (a0.x == m0); oa0.y = (a0.y == m0); oa0.z = (a0.z == m0); oa0.w = (a0.w == m0);
        ob0.x = (b0.x == m0); ob0.y = (b0.y == m0); ob0.z = (b0.z == m0); ob0.w = (b0.w == m0);
        oa1.x = (a1.x == m1); oa1.y = (a1.y == m1); oa1.z = (a1.z == m1); oa1.w = (a1.w == m1);
        ob1.x = (b1.x == m1); ob1.y = (b1.y == m1); ob1.z = (b1.z == m1); ob1.w = (b1.w == m1);

        i32x4* w0 = reinterpret_cast<i32x4*>(out + (size_t)row * 512);
        i32x4* w1 = reinterpret_cast<i32x4*>(out + (size_t)(row + 1) * 512);
        __builtin_nontemporal_store(oa0, w0 + lane);
        __builtin_nontemporal_store(ob0, w0 + lane + 64);
        __builtin_nontemporal_store(oa1, w1 + lane);
        __builtin_nontemporal_store(ob1, w1 + lane + 64);

        if (nrow >= nrows) break;
        row = nrow;
        a0 = na0; b0 = nb0; a1 = na1; b1 = nb1;
    }
}

extern "C" void kernel_launch(void* const* d_in, const int* in_sizes, int n_in,
                              void* d_out, int out_size, void* d_ws, size_t ws_size,
                              hipStream_t stream) {
    const float* in = (const float*)d_in[0];
    int* out = (int*)d_out;
    const int D = 512;
    const int nrows = in_sizes[0] / D;   // 200704
    int grid = 2048;                     // 8 blocks/CU = all 32 wave slots
    const int max_needed = (nrows + 7) / 8;  // 4 waves/block * 2 rows/wave
    if (grid > max_needed) grid = max_needed;
    rowmax_mask_kernel<<<grid, 256, 0, stream>>>(in, out, nrows);
}